// Round 3
// baseline (493.990 us; speedup 1.0000x reference)
//
#include <hip/hip_runtime.h>
#include <hip/hip_bf16.h>
#include <cstdint>
#include <cstddef>

// IR-Net binary conv 3x3 s1 p1 + BN(inference) + hardtanh, B=32 Cin=Cout=256 H=W=56.
// sign(x), sign(std(W)) ternary -> exact bf16 MFMA implicit GEMM.
// R3: W in fragment-order global buffer (coalesced reg loads, no W LDS/barriers),
//     block 256co x 128px, barrier only per cin-block (4/block, 576 MFMA between),
//     halo-clear kernel instead of 55MB memset.

typedef short short8 __attribute__((ext_vector_type(8)));
typedef float floatx4 __attribute__((ext_vector_type(4)));

#define CIN   256
#define COUT  256
#define SPAT  3136   // 56*56
#define SPAD  3364   // 58*58 padded spatial
#define BATCH 32
#define SPAN  256    // padded-index rows staged per 128-px tile (halo included)

// ---------------- weight prep: standardize, sign, scatter to fragment order ----------------
__device__ inline float block_reduce(float v, float* red, int t) {
  red[t] = v; __syncthreads();
#pragma unroll
  for (int o = 128; o > 0; o >>= 1) {
    if (t < o) red[t] += red[t + o];
    __syncthreads();
  }
  float r = red[0];
  __syncthreads();
  return r;
}

__global__ __launch_bounds__(256) void prep_w_kernel(
    const float* __restrict__ wgt, const float* __restrict__ gamma,
    const float* __restrict__ beta, const float* __restrict__ rmean,
    const float* __restrict__ rvar, uint16_t* __restrict__ wfrag,
    float* __restrict__ Sc, float* __restrict__ Tc) {
  const int co = blockIdx.x;
  const int t  = threadIdx.x;
  __shared__ float red[256];
  const float* wc = wgt + (size_t)co * 2304;
  float v[9];
#pragma unroll
  for (int j = 0; j < 9; ++j) v[j] = wc[t + j * 256];
  float s = 0.f;
#pragma unroll
  for (int j = 0; j < 9; ++j) s += v[j];
  const float total = block_reduce(s, red, t);
  const float mean = total * (1.0f / 2304.0f);
  float ss = 0.f, sa = 0.f;
#pragma unroll
  for (int j = 0; j < 9; ++j) {
    float d = v[j] - mean;
    ss += d * d;
    sa += fabsf(d);
  }
  const float var_sum = block_reduce(ss, red, t);
  const float abs_sum = block_reduce(sa, red, t);
  const float stdv = sqrtf(var_sum / 2303.0f);       // unbiased (ddof=1)
  const float mean_abs = abs_sum / (2304.0f * stdv); // mean |bw|
  const float sw = exp2f(rintf(log2f(mean_abs)));    // half-even like jnp.round

  const int gco = co >> 6, mm = (co >> 4) & 3, l15w = co & 15;
#pragma unroll
  for (int j = 0; j < 9; ++j) {
    int i = t + j * 256;          // i = cin*9 + tap  (OIHW flat)
    int cin = i / 9;
    int tap = i - cin * 9;
    float d = v[j] - mean;
    uint16_t bits = (d > 0.f) ? 0x3F80u : ((d < 0.f) ? 0xBF80u : 0u); // bf16 +-1 / 0
    // fragment-order address: [tap][c0i][gco][kk][m][lane][elem]
    int c0i = cin >> 6, c = cin & 63;
    int chunk = c >> 3, kk = chunk >> 2, chpos = chunk & 3, elem = c & 7;
    int lanew = l15w | (chpos << 4);
    size_t flat = ((((size_t)((tap * 4 + c0i) * 4 + gco) * 2 + kk) * 4 + mm) * 64 + lanew) * 8 + elem;
    wfrag[flat] = bits;
  }
  if (t == 0) {
    float inv = gamma[co] / sqrtf(rvar[co] + 1e-5f);
    Sc[co] = sw * inv;
    Tc[co] = beta[co] - rmean[co] * inv;
  }
}

// ---------------- halo clear: zero only the 228 pad pixels per image ----------------
__global__ __launch_bounds__(256) void halo_kernel(uint16_t* __restrict__ xp) {
  const int b = blockIdx.x;
  uint16_t* xpb = xp + (size_t)b * SPAD * CIN;
  const short8 z = (short8){0, 0, 0, 0, 0, 0, 0, 0};
  for (int q = threadIdx.x; q < 228 * 32; q += 256) {
    int p = q >> 5, c = q & 31;
    int pp;
    if (p < 58)       pp = p;                      // top row 0
    else if (p < 116) pp = 57 * 58 + (p - 58);     // bottom row 57
    else if (p < 172) pp = (p - 116 + 1) * 58;     // left col, rows 1..56
    else              pp = (p - 172 + 1) * 58 + 57;// right col, rows 1..56
    *(short8*)(xpb + (size_t)pp * CIN + c * 8) = z;
  }
}

// ---------------- activation pack: sign(x) -> bf16, padded [b][58*58][cin] ----------------
__global__ __launch_bounds__(256) void pack_x_kernel(const float* __restrict__ x,
                                                     uint16_t* __restrict__ xp) {
  const int b   = blockIdx.y;
  const int s0  = blockIdx.x * 64;
  const int tid = threadIdx.x;
  __shared__ uint16_t xt[64][272];
  const int g  = tid >> 6;
  const int si = tid & 63;
  const float* xb = x + ((size_t)b * CIN + g * 64) * SPAT + s0 + si;
#pragma unroll 4
  for (int c2 = 0; c2 < 32; ++c2) {
    float v0 = xb[(size_t)(2 * c2) * SPAT];
    float v1 = xb[(size_t)(2 * c2 + 1) * SPAT];
    uint32_t b0 = (v0 > 0.f) ? 0x3F80u : ((v0 < 0.f) ? 0xBF80u : 0u);
    uint32_t b1 = (v1 > 0.f) ? 0x3F80u : ((v1 < 0.f) ? 0xBF80u : 0u);
    *(uint32_t*)&xt[si][g * 64 + 2 * c2] = b0 | (b1 << 16);
  }
  __syncthreads();
  const int row = tid >> 2;
  const int sub = tid & 3;
  const int s = s0 + row;
  const int h = s / 56, w = s - h * 56;
  uint16_t* dst = xp + ((size_t)b * SPAD + (size_t)(h + 1) * 58 + (w + 1)) * CIN + sub * 64;
#pragma unroll
  for (int j = 0; j < 8; ++j)
    *(short8*)(dst + j * 8) = *(const short8*)&xt[row][sub * 64 + j * 8];
}

// ---------------- async global->LDS, 16B ----------------
__device__ __forceinline__ void gload_lds16(const void* g, void* l) {
  __builtin_amdgcn_global_load_lds(
      (const __attribute__((address_space(1))) uint32_t*)g,
      (__attribute__((address_space(3))) uint32_t*)l, 16, 0, 0);
}

// ---------------- binary conv as implicit GEMM (bf16 MFMA) ----------------
// Block: 256 co x 128 px, one image; 4 waves, wave = one 64-co quadrant (gco).
// X: padded-span [SPAN][64cin] XOR-swizzled in LDS, reused across 9 taps.
// W: fragment-order global buffer, coalesced dwordx4 loads straight to regs.
__global__ __launch_bounds__(256, 2) void conv_kernel(
    const uint16_t* __restrict__ xp, const uint16_t* __restrict__ wfrag,
    const float* __restrict__ Sc, const float* __restrict__ Tc,
    float* __restrict__ out) {
  const int tile = blockIdx.x;           // 0..24
  const int b    = blockIdx.y;           // 0..31
  const int s0   = tile * 128;

  const int tid  = threadIdx.x;
  const int lane = tid & 63;
  const int gco  = tid >> 6;             // wave's co quadrant
  const int l15  = lane & 15;
  const int chp  = lane >> 4;            // k-chunk position 0..3

  __shared__ uint16_t Xs[2][SPAN * 64];  // 64 KB

  const int h0   = s0 / 56;
  const int base = s0 + 2 * h0;          // padded(s0) - 59, padded(s)=s+2h+59

  // per-lane px padded offsets (n=0..7); dummy px clamped (stores masked)
  int offn[8];
#pragma unroll
  for (int n = 0; n < 8; ++n) {
    int s = s0 + n * 16 + l15;
    int sc = s < SPAT ? s : SPAT - 1;
    int h = sc / 56;
    offn[n] = sc + 2 * h + 59 - base;
  }

  const uint16_t* xb = xp + (size_t)b * SPAD * CIN;
  auto issueX = [&](int bufi, int c0e) {
#pragma unroll
    for (int j = 0; j < 8; ++j) {
      int q = j * 256 + tid;             // 2048 x 16B chunks
      int row = q >> 3, c = q & 7;
      int gr = base + row;
      if (gr > SPAD - 1) gr = SPAD - 1;  // clamp: only feeds dummy px
      gload_lds16(xb + (size_t)gr * CIN + c0e + ((c ^ (row & 7)) << 3),
                  &Xs[bufi][q << 3]);
    }
  };

  floatx4 acc[4][8];
#pragma unroll
  for (int m = 0; m < 4; ++m)
#pragma unroll
    for (int n = 0; n < 8; ++n) acc[m][n] = (floatx4){0.f, 0.f, 0.f, 0.f};

  issueX(0, 0);
  __syncthreads();                       // vmcnt(0) drain: Xs[0] ready

  for (int c0i = 0; c0i < 4; ++c0i) {
    const int buf = c0i & 1;
    if (c0i < 3) issueX(buf ^ 1, (c0i + 1) * 64);  // in flight across 9 taps

    const uint16_t* wc0p = wfrag + (size_t)c0i * 16384 + (size_t)gco * 4096
                         + (size_t)lane * 8;
#pragma unroll
    for (int tap = 0; tap < 9; ++tap) {
      const int tapoff = (tap / 3) * 58 + (tap - (tap / 3) * 3) - 59;
      const uint16_t* wt = wc0p + (size_t)tap * 65536;
      int xaddr[8], xsw[8];
#pragma unroll
      for (int n = 0; n < 8; ++n) {
        int r = offn[n] + tapoff;
        xaddr[n] = r << 6;
        xsw[n] = r & 7;
      }
#pragma unroll
      for (int kk = 0; kk < 2; ++kk) {
        const int cb = kk * 4 + chp;
        short8 af[4], bf[8];
#pragma unroll
        for (int m = 0; m < 4; ++m)
          af[m] = *(const short8*)(wt + kk * 2048 + m * 512);
#pragma unroll
        for (int n = 0; n < 8; ++n)
          bf[n] = *(const short8*)&Xs[buf][xaddr[n] + ((cb ^ xsw[n]) << 3)];
#pragma unroll
        for (int m = 0; m < 4; ++m)
#pragma unroll
          for (int n = 0; n < 8; ++n)
            acc[m][n] = __builtin_amdgcn_mfma_f32_16x16x32_bf16(af[m], bf[n], acc[m][n], 0, 0, 0);
      }
    }
    __syncthreads();                     // readers done + next Xs buf drained
  }

  // epilogue: out = clip(acc*S + T), layout [b][co][s]
#pragma unroll
  for (int m = 0; m < 4; ++m) {
    const int cor0 = gco * 64 + m * 16 + chp * 4;
    float Sv[4], Tv[4];
#pragma unroll
    for (int r = 0; r < 4; ++r) { Sv[r] = Sc[cor0 + r]; Tv[r] = Tc[cor0 + r]; }
#pragma unroll
    for (int n = 0; n < 8; ++n) {
      const int s = s0 + n * 16 + l15;
      if (s < SPAT) {
        float* op = out + ((size_t)b * COUT + cor0) * SPAT + s;
#pragma unroll
        for (int r = 0; r < 4; ++r) {
          float v = acc[m][n][r] * Sv[r] + Tv[r];
          v = fminf(1.0f, fmaxf(-1.0f, v));
          op[(size_t)r * SPAT] = v;
        }
      }
    }
  }
}

extern "C" void kernel_launch(void* const* d_in, const int* in_sizes, int n_in,
                              void* d_out, int out_size, void* d_ws, size_t ws_size,
                              hipStream_t stream) {
  const float* x     = (const float*)d_in[0];
  const float* wgt   = (const float*)d_in[1];
  const float* gamma = (const float*)d_in[2];
  const float* beta  = (const float*)d_in[3];
  const float* rmean = (const float*)d_in[4];
  const float* rvar  = (const float*)d_in[5];
  float* out = (float*)d_out;

  uint16_t* xp = (uint16_t*)d_ws;
  const size_t xp_elems = (size_t)BATCH * SPAD * CIN;        // 55.1 MB
  uint16_t* wfrag = xp + xp_elems;
  const size_t wfrag_elems = (size_t)9 * COUT * CIN;         // 1.2 MB
  float* Sc = (float*)(wfrag + wfrag_elems);
  float* Tc = Sc + COUT;

  halo_kernel<<<BATCH, 256, 0, stream>>>(xp);
  pack_x_kernel<<<dim3(49, BATCH), 256, 0, stream>>>(x, xp);
  prep_w_kernel<<<COUT, 256, 0, stream>>>(wgt, gamma, beta, rmean, rvar, wfrag, Sc, Tc);
  conv_kernel<<<dim3(25, BATCH), 256, 0, stream>>>(xp, wfrag, Sc, Tc, out);
}